// Round 6
// baseline (572.677 us; speedup 1.0000x reference)
//
#include <hip/hip_runtime.h>
#include <hip/hip_bf16.h>

// C2QAttention: softmax(sim[B,C,Q], axis=Q) @ enc[B,Q,D] -> out[B,C,D]
// B=32, C=4096, Q=512, D=512. fp32 in/out; bf16 MFMA, deferred normalization:
// out = (exp(sim) @ enc) * (1/rowsum).
//
// Round 6: round-5 structure (barrier/LDS-free, direct A-frag loads, fragment-
// major Et, b-pinned XCD grid) + explicit 2-deep software pipeline:
//   step ks: exp/pack(batch ks) | issue sim ks+2 | issue B-frags ks+1 | MFMA ks
// Fully unrolled so all double-buffer indices are compile-time constants.

constexpr int Bn = 32;
constexpr int Cn = 4096;
constexpr int Qn = 512;
constexpr int Dn = 512;

typedef __attribute__((ext_vector_type(8))) short short8;
typedef __attribute__((ext_vector_type(4))) float floatx4;

__device__ __forceinline__ ushort f2bf(float f) {
  union { float f; unsigned u; } v; v.f = f;
  unsigned r = v.u + 0x7FFFu + ((v.u >> 16) & 1u);   // RNE
  return (ushort)(r >> 16);
}

// enc[b][q][d] f32 -> Etf fragment-major: [b][dtile(32)][ks(16)][lane(64)]x16B
// chunk(b,dt,ks): lane=lhi*16+l16 holds bf16[j] = enc[b][ks*32+lhi*8+j][dt*16+l16]
__global__ __launch_bounds__(256) void enc_to_frag(const float* __restrict__ E,
                                                   ushort* __restrict__ Etf) {
  const int ks = blockIdx.x, b = blockIdx.y;
  const int t = threadIdx.x;
  const int lane = t & 63, grp = t >> 6;
  const int l16 = lane & 15, lhi = lane >> 4;
  const float* src = E + ((size_t)b * Qn + ks * 32 + lhi * 8) * Dn + l16;
#pragma unroll
  for (int dt8 = 0; dt8 < 8; ++dt8) {
    int dt = grp * 8 + dt8;
    float e[8];
#pragma unroll
    for (int j = 0; j < 8; ++j) e[j] = src[(size_t)j * Dn + dt * 16];
    uint4 pk;
    pk.x = (uint)f2bf(e[0]) | ((uint)f2bf(e[1]) << 16);
    pk.y = (uint)f2bf(e[2]) | ((uint)f2bf(e[3]) << 16);
    pk.z = (uint)f2bf(e[4]) | ((uint)f2bf(e[5]) << 16);
    pk.w = (uint)f2bf(e[6]) | ((uint)f2bf(e[7]) << 16);
    *(uint4*)((char*)Etf + (((size_t)(b * 32 + dt) * 16 + ks) * 64 + lane) * 16) = pk;
  }
}

__global__ __launch_bounds__(256, 2) void c2q_fused(const float* __restrict__ sim,
                                                    const ushort* __restrict__ Etf,
                                                    float* __restrict__ out) {
  const int t    = threadIdx.x;
  const int lane = t & 63;
  const int w    = t >> 6;             // 0..3 -> 128 D-cols each
  const int l16  = lane & 15;
  const int lhi  = lane >> 4;          // 0..3

  // b-pinned XCD grid: XCD = lin%8 serves b in {blo, 8+blo, 16+blo, 24+blo}
  const int lin  = blockIdx.x;         // 4096 blocks
  const int blo  = lin & 7;
  const int rest = lin >> 3;
  const int bhi  = rest & 3;
  const int ct   = rest >> 2;          // 0..127
  const int b    = (bhi << 3) | blo;
  const int c0   = ct * 32;
  const int d0   = w * 128;

  // direct A-frag load bases (mr = 0,1): row = c0 + mr*16 + l16, k = lhi*8
  const float* s0 = sim + ((size_t)b * Cn + c0 + l16) * Qn + lhi * 8;
  const float* s1 = s0 + (size_t)16 * Qn;

  // B-frag base: chunk (b, dtile = w*8 + nr, ks), this lane's 16B
  const short8* EB = (const short8*)Etf + (((size_t)b * 32 + w * 8) * 16) * 64 + lane;

  floatx4 acc[2][8] = {};
  float r0 = 0.0f, r1 = 0.0f;

  // pipeline state: sim double-buffer (slot = ks&1), B-frag double-buffer
  float4 v[2][2][2];   // [slot][mr][half]
  short8 bb[2][8];     // [slot][nr]

  // ---- prologue: sim ks=0,1 ; B-frags ks=0 ----
#pragma unroll
  for (int sl = 0; sl < 2; ++sl) {
    v[sl][0][0] = *(const float4*)(s0 + sl * 32);
    v[sl][0][1] = *(const float4*)(s0 + sl * 32 + 4);
    v[sl][1][0] = *(const float4*)(s1 + sl * 32);
    v[sl][1][1] = *(const float4*)(s1 + sl * 32 + 4);
  }
#pragma unroll
  for (int nr = 0; nr < 8; ++nr) bb[0][nr] = EB[(size_t)nr * 16 * 64];

#pragma unroll
  for (int ks = 0; ks < 16; ++ks) {
    const int sl = ks & 1;

    // (1) exp + pack a-frags from batch ks (loaded 2 iters ago)
    short8 a[2];
#pragma unroll
    for (int mr = 0; mr < 2; ++mr) {
      float4 x = v[sl][mr][0], y = v[sl][mr][1];
      float e0 = __expf(x.x), e1 = __expf(x.y), e2 = __expf(x.z), e3 = __expf(x.w);
      float e4 = __expf(y.x), e5 = __expf(y.y), e6 = __expf(y.z), e7 = __expf(y.w);
      float s = ((e0 + e1) + (e2 + e3)) + ((e4 + e5) + (e6 + e7));
      if (mr == 0) r0 += s; else r1 += s;
      union { uint4 u; short8 s8; } pk;
      pk.u.x = (uint)f2bf(e0) | ((uint)f2bf(e1) << 16);
      pk.u.y = (uint)f2bf(e2) | ((uint)f2bf(e3) << 16);
      pk.u.z = (uint)f2bf(e4) | ((uint)f2bf(e5) << 16);
      pk.u.w = (uint)f2bf(e6) | ((uint)f2bf(e7) << 16);
      a[mr] = pk.s8;
    }

    // (2) issue sim loads for ks+2 into the slot just freed
    if (ks < 14) {
      v[sl][0][0] = *(const float4*)(s0 + (ks + 2) * 32);
      v[sl][0][1] = *(const float4*)(s0 + (ks + 2) * 32 + 4);
      v[sl][1][0] = *(const float4*)(s1 + (ks + 2) * 32);
      v[sl][1][1] = *(const float4*)(s1 + (ks + 2) * 32 + 4);
    }

    // (3) issue B-frag loads for ks+1 (L2-resident)
    if (ks < 15) {
#pragma unroll
      for (int nr = 0; nr < 8; ++nr)
        bb[sl ^ 1][nr] = EB[((size_t)nr * 16 + (ks + 1)) * 64];
    }

    // keep load issue above the MFMA cluster
    __builtin_amdgcn_sched_barrier(0);

    // (4) MFMA ks
    __builtin_amdgcn_s_setprio(1);
#pragma unroll
    for (int mr = 0; mr < 2; ++mr)
#pragma unroll
      for (int nr = 0; nr < 8; ++nr)
        acc[mr][nr] = __builtin_amdgcn_mfma_f32_16x16x32_bf16(a[mr], bb[sl][nr],
                                                              acc[mr][nr], 0, 0, 0);
    __builtin_amdgcn_s_setprio(0);
  }

  // rowsums: lanes {l16, l16+16, l16+32, l16+48} hold partials of row l16
  r0 += __shfl_xor(r0, 16); r0 += __shfl_xor(r0, 32);
  r1 += __shfl_xor(r1, 16); r1 += __shfl_xor(r1, 32);
  float inv0 = 1.0f / r0, inv1 = 1.0f / r1;

  float* outp = out + ((size_t)b * Cn + c0) * Dn + d0;
#pragma unroll
  for (int mr = 0; mr < 2; ++mr) {
    float rs[4];
#pragma unroll
    for (int rr = 0; rr < 4; ++rr)
      rs[rr] = __shfl(mr == 0 ? inv0 : inv1, lhi * 4 + rr);
#pragma unroll
    for (int nr = 0; nr < 8; ++nr) {
#pragma unroll
      for (int rr = 0; rr < 4; ++rr) {
        int row = mr * 16 + lhi * 4 + rr;
        outp[(size_t)row * Dn + nr * 16 + l16] = acc[mr][nr][rr] * rs[rr];
      }
    }
  }
}

extern "C" void kernel_launch(void* const* d_in, const int* in_sizes, int n_in,
                              void* d_out, int out_size, void* d_ws, size_t ws_size,
                              hipStream_t stream) {
  const float* sim = (const float*)d_in[0];
  const float* enc = (const float*)d_in[1];
  float* outp = (float*)d_out;
  ushort* Etf = (ushort*)d_ws;  // 32*32*16*64*16 B = 16.8 MB

  enc_to_frag<<<dim3(16, Bn), 256, 0, stream>>>(enc, Etf);
  c2q_fused<<<dim3(4096), 256, 0, stream>>>(sim, Etf, outp);
}

// Round 7
// 165.603 us; speedup vs baseline: 3.4581x; 3.4581x over previous
//
#include <hip/hip_runtime.h>
#include <hip/hip_bf16.h>

// C2QAttention: softmax(sim[B,C,Q], axis=Q) @ enc[B,Q,D] -> out[B,C,D]
// B=32, C=4096, Q=512, D=512. fp32 in/out; bf16 MFMA, deferred normalization.
// Round 7: block = 64 C-rows x full D (sim read once). K pipelined: 8 steps of
// BK=64, double-buffered 8KB LDS A-tile, sim loads 2 steps ahead (2 float4/thr),
// exp+pack+ds_write at step end, 1 barrier/step, 256 MFMA/block/step.
// B-frags: 2-deep prefetch from L2-resident fragment-major Etf (b-pinned XCDs).

constexpr int Bn = 32;
constexpr int Cn = 4096;
constexpr int Qn = 512;
constexpr int Dn = 512;

typedef __attribute__((ext_vector_type(8))) short short8;
typedef __attribute__((ext_vector_type(4))) float floatx4;

__device__ __forceinline__ ushort f2bf(float f) {
  union { float f; unsigned u; } v; v.f = f;
  unsigned r = v.u + 0x7FFFu + ((v.u >> 16) & 1u);   // RNE
  return (ushort)(r >> 16);
}

__device__ __forceinline__ uint4 exp_pack(float4 x, float4 y, float& rsum) {
  float e0 = __expf(x.x), e1 = __expf(x.y), e2 = __expf(x.z), e3 = __expf(x.w);
  float e4 = __expf(y.x), e5 = __expf(y.y), e6 = __expf(y.z), e7 = __expf(y.w);
  rsum += ((e0 + e1) + (e2 + e3)) + ((e4 + e5) + (e6 + e7));
  uint4 pk;
  pk.x = (uint)f2bf(e0) | ((uint)f2bf(e1) << 16);
  pk.y = (uint)f2bf(e2) | ((uint)f2bf(e3) << 16);
  pk.z = (uint)f2bf(e4) | ((uint)f2bf(e5) << 16);
  pk.w = (uint)f2bf(e6) | ((uint)f2bf(e7) << 16);
  return pk;
}

// enc[b][q][d] f32 -> Etf fragment-major: [b][dtile(32)][kidx(16)][lane(64)]x16B
// chunk(b,dt,kidx): lane=lhi*16+l16 holds bf16[j]=enc[b][kidx*32+lhi*8+j][dt*16+l16]
__global__ __launch_bounds__(256) void enc_to_frag(const float* __restrict__ E,
                                                   ushort* __restrict__ Etf) {
  const int ks = blockIdx.x, b = blockIdx.y;
  const int t = threadIdx.x;
  const int lane = t & 63, grp = t >> 6;
  const int l16 = lane & 15, lhi = lane >> 4;
  const float* src = E + ((size_t)b * Qn + ks * 32 + lhi * 8) * Dn + l16;
#pragma unroll
  for (int dt8 = 0; dt8 < 8; ++dt8) {
    int dt = grp * 8 + dt8;
    float e[8];
#pragma unroll
    for (int j = 0; j < 8; ++j) e[j] = src[(size_t)j * Dn + dt * 16];
    uint4 pk;
    pk.x = (uint)f2bf(e[0]) | ((uint)f2bf(e[1]) << 16);
    pk.y = (uint)f2bf(e[2]) | ((uint)f2bf(e[3]) << 16);
    pk.z = (uint)f2bf(e[4]) | ((uint)f2bf(e[5]) << 16);
    pk.w = (uint)f2bf(e[6]) | ((uint)f2bf(e[7]) << 16);
    *(uint4*)((char*)Etf + (((size_t)(b * 32 + dt) * 16 + ks) * 64 + lane) * 16) = pk;
  }
}

__global__ __launch_bounds__(512, 2) void c2q_fused(const float* __restrict__ sim,
                                                    const ushort* __restrict__ Etf,
                                                    float* __restrict__ out) {
  __shared__ char Abuf[2][64 * 128];   // [buf][row*128B] bf16, XOR-swizzled
  __shared__ float rsInv[64];

  const int tid  = threadIdx.x;
  const int lane = tid & 63;
  const int wid  = tid >> 6;           // 0..7 -> 64 D-cols each
  const int l16  = lane & 15;
  const int lhi  = lane >> 4;          // 0..3

  // b-pinned XCD grid: XCD = lin&7 -> 4 b per XCD, Et 2MB per XCD L2
  const int lin = blockIdx.x;          // 2048 = 64 mtiles x 32 b
  const int blo = lin & 7;
  const int bhi = (lin >> 3) & 3;
  const int mt  = lin >> 5;
  const int b   = bhi * 8 + blo;
  const int c0  = mt * 64;

  // staging: thread owns (row srow, k-octet so): 8 floats per step
  const int srow = tid >> 3;           // 0..63
  const int so   = tid & 7;            // 0..7
  const float* sload = sim + ((size_t)b * Cn + c0 + srow) * Qn + so * 8;
  const int swa = (srow * 128 + so * 16) ^ ((srow & 7) << 4);

  // B-frag base: chunk (b, dt = wid*4 + nr, kidx), this lane's 16B
  const short8* EB = (const short8*)Etf + ((size_t)(b * 32 + wid * 4) * 16) * 64 + lane;

  float rsum = 0.0f;
  floatx4 acc[4][4] = {};
  float4 vs[2][2];                     // 2 slots x 2 float4 (static-indexed)
  short8 bfr[2][4];                    // B-frag 2-deep rotate

  // ---- prologue: data(0) -> Abuf[0]; data(1) -> slot1; B kidx 0,1 ----
  vs[0][0] = *(const float4*)(sload);
  vs[0][1] = *(const float4*)(sload + 4);
  vs[1][0] = *(const float4*)(sload + 64);
  vs[1][1] = *(const float4*)(sload + 68);
#pragma unroll
  for (int nr = 0; nr < 4; ++nr) {
    bfr[0][nr] = EB[((size_t)nr * 16 + 0) * 64];
    bfr[1][nr] = EB[((size_t)nr * 16 + 1) * 64];
  }
  *(uint4*)(Abuf[0] + swa) = exp_pack(vs[0][0], vs[0][1], rsum);
  __syncthreads();

#pragma unroll
  for (int t = 0; t < 8; ++t) {
    // (a) issue sim loads for step t+2 into the slot freed at step t-1
    if (t < 6) {
      vs[t & 1][0] = *(const float4*)(sload + (t + 2) * 64);
      vs[t & 1][1] = *(const float4*)(sload + (t + 2) * 64 + 4);
    }
    __builtin_amdgcn_sched_barrier(0);

    // (b) MFMA on Abuf[t&1], 2 k-slices of 32
#pragma unroll
    for (int ks = 0; ks < 2; ++ks) {
      const int kidx = 2 * t + ks;
      short8 a[4];
#pragma unroll
      for (int mr = 0; mr < 4; ++mr) {
        int row = mr * 16 + l16;
        a[mr] = *(const short8*)(Abuf[t & 1] +
                 ((row * 128 + ks * 64 + lhi * 16) ^ ((row & 7) << 4)));
      }
      __builtin_amdgcn_s_setprio(1);
#pragma unroll
      for (int mr = 0; mr < 4; ++mr)
#pragma unroll
        for (int nr = 0; nr < 4; ++nr)
          acc[mr][nr] = __builtin_amdgcn_mfma_f32_16x16x32_bf16(
              a[mr], bfr[kidx & 1][nr], acc[mr][nr], 0, 0, 0);
      __builtin_amdgcn_s_setprio(0);
      // refill just-consumed B slot with kidx+2 (2-deep, L2-resident)
      if (kidx < 14) {
#pragma unroll
        for (int nr = 0; nr < 4; ++nr)
          bfr[kidx & 1][nr] = EB[((size_t)nr * 16 + kidx + 2) * 64];
      }
    }

    // (c) exp + stage data(t+1) into Abuf[(t+1)&1]; last step: finalize rowsum
    if (t < 7) {
      *(uint4*)(Abuf[(t + 1) & 1] + swa) =
          exp_pack(vs[(t + 1) & 1][0], vs[(t + 1) & 1][1], rsum);
    } else {
      rsum += __shfl_xor(rsum, 1);
      rsum += __shfl_xor(rsum, 2);
      rsum += __shfl_xor(rsum, 4);
      if (so == 0) rsInv[srow] = 1.0f / rsum;
    }
    __syncthreads();
  }

  // ---- epilogue: scale by 1/rowsum, store ----
  float* outp = out + ((size_t)b * Cn + c0) * Dn + wid * 64;
#pragma unroll
  for (int mr = 0; mr < 4; ++mr) {
    float rs[4];
#pragma unroll
    for (int rr = 0; rr < 4; ++rr) rs[rr] = rsInv[mr * 16 + lhi * 4 + rr];
#pragma unroll
    for (int nr = 0; nr < 4; ++nr) {
#pragma unroll
      for (int rr = 0; rr < 4; ++rr) {
        int row = mr * 16 + lhi * 4 + rr;
        outp[(size_t)row * Dn + nr * 16 + l16] = acc[mr][nr][rr] * rs[rr];
      }
    }
  }
}

extern "C" void kernel_launch(void* const* d_in, const int* in_sizes, int n_in,
                              void* d_out, int out_size, void* d_ws, size_t ws_size,
                              hipStream_t stream) {
  const float* sim = (const float*)d_in[0];
  const float* enc = (const float*)d_in[1];
  float* outp = (float*)d_out;
  ushort* Etf = (ushort*)d_ws;  // 32*32*16*64*16 B = 16.8 MB

  enc_to_frag<<<dim3(16, Bn), 256, 0, stream>>>(enc, Etf);
  c2q_fused<<<dim3(2048), 512, 0, stream>>>(sim, Etf, outp);
}